// Round 5
// baseline (742.111 us; speedup 1.0000x reference)
//
#include <hip/hip_runtime.h>
#include <hip/hip_bf16.h>
#include <stdint.h>

typedef __attribute__((ext_vector_type(8))) short short8;
typedef __attribute__((ext_vector_type(4))) float f32x4;
typedef __attribute__((ext_vector_type(4))) float float4v;
typedef __attribute__((ext_vector_type(4))) int int4v;

#define MDIM 8192
#define NDIM 11008
#define KDIM 4096
#define NT   (KDIM / 64)      /* 64 K-tiles */
#define NBM2 (MDIM / 256)     /* 32 */
#define NBN2 (NDIM / 256)     /* 43 */

static __device__ __forceinline__ unsigned short f2bf(float f) {
  union { float f; unsigned int u; } v;
  v.f = f;
  unsigned int r = v.u + 0x7FFFu + ((v.u >> 16) & 1u);
  return (unsigned short)(r >> 16);
}

#define GLDS16(g, l) __builtin_amdgcn_global_load_lds(                         \
    (const __attribute__((address_space(1))) void*)(g),                        \
    (__attribute__((address_space(3))) void*)(l), 16, 0, 0)

// ---------------- pass 1: x fp32 -> bf16  AND  qweight -> bf16 (one launch) --
#define XBLOCKS ((MDIM * (size_t)KDIM) / (8 * 256))   /* 16384 */
#define WBLOCKS ((NDIM * (size_t)KDIM) / (8 * 256))   /* 22016 */

__global__ __launch_bounds__(256) void conv_all(
    const float* __restrict__ x, unsigned short* __restrict__ xb,
    const int* __restrict__ qw, const float* __restrict__ scale,
    unsigned short* __restrict__ wb) {
  if (blockIdx.x < XBLOCKS) {
    const size_t i = ((size_t)blockIdx.x * 256 + threadIdx.x) * 8;
    float4v v0 = *(const float4v*)(x + i);
    float4v v1 = *(const float4v*)(x + i + 4);
    short8 o;
#pragma unroll
    for (int e = 0; e < 4; ++e) { o[e] = (short)f2bf(v0[e]); o[4 + e] = (short)f2bf(v1[e]); }
    *(short8*)(xb + i) = o;
  } else {
    const size_t i = (((size_t)blockIdx.x - XBLOCKS) * 256 + threadIdx.x) * 8;
    int4v q0 = *(const int4v*)(qw + i);
    int4v q1 = *(const int4v*)(qw + i + 4);
    const float inv = 1.0f / scale[i >> 8];
    short8 o;
#pragma unroll
    for (int e = 0; e < 4; ++e) {
      o[e]     = (short)f2bf((float)q0[e] * inv);
      o[4 + e] = (short)f2bf((float)q1[e] * inv);
    }
    *(short8*)(wb + i) = o;
  }
}

// ---------------- pass 2: 256x256 multi-phase bf16 GEMM ----------------
__global__ __launch_bounds__(512, 2) void gemm256(
    const unsigned short* __restrict__ xa,
    const unsigned short* __restrict__ wb,
    const float* __restrict__ bias,
    float* __restrict__ out)
{
  __shared__ unsigned char lds[131072];
  unsigned char* ldsA = lds;            // [2][32768]: 256 rows x 64 bf16, swizzled slots
  unsigned char* ldsB = lds + 65536;    // [2][32768]

  const int t = threadIdx.x;
  const int lane = t & 63;
  const int w = t >> 6;        // wave 0..7
  const int wr = w >> 2;       // 0..1  (A half)
  const int wc = w & 3;        // 0..3  (B quarter)
  const int lh = lane >> 4;    // 0..3
  const int l15 = lane & 15;
  const int l7 = lane & 7;
  const int lr = lane >> 3;    // 0..7 staging row within 8-row strip

  // XCD-bijective swizzle: 1376 = 8 * 172
  const int bid = blockIdx.x;
  const int swz = (bid & 7) * (NBM2 * NBN2 / 8) + (bid >> 3);
  const int bm = swz / NBN2;
  const int bn = swz % NBN2;

  // per-lane LDS read base: row-part l15*128, slot ((ks*4+lh)^l7)<<4; ks flips bit 6
  const int rdBase0 = l15 * 128 + ((lh ^ l7) << 4);

  // staging: linear LDS dest (base+lane*16) <- pre-swizzled global source
  // phys (row=lr, slot=l7) holds logical col8 = l7 ^ lr
  const size_t srcOff = (size_t)lr * KDIM + ((l7 ^ lr) << 3);

  const unsigned short* aS = xa + ((size_t)(bm * 256 + wr * 128 + wc * 8)) * KDIM + srcOff;
  const unsigned short* bS = wb + ((size_t)(bn * 256 + w * 32)) * KDIM + srcOff;
  const int aDst = (wr * 128 + wc * 8) * 128;   // + q*4096 + cur*32768
  const int bDst = (w * 32) * 128;              // + c*1024 + cur*32768

  float bias_v[4];
#pragma unroll
  for (int n = 0; n < 4; ++n) bias_v[n] = bias[bn * 256 + wc * 64 + n * 16 + l15];

  f32x4 acc[8][4];
#pragma unroll
  for (int m = 0; m < 8; ++m)
#pragma unroll
    for (int n = 0; n < 4; ++n) acc[m][n] = (f32x4){0.f, 0.f, 0.f, 0.f};

#define STAGE_B4(cur, kt) {                                                    \
  _Pragma("unroll")                                                            \
  for (int c = 0; c < 4; ++c)                                                  \
    GLDS16(bS + (size_t)(c * 8) * KDIM + (kt) * 64,                            \
           ldsB + (cur) * 32768 + bDst + c * 1024); }
#define STAGE_A1(cur, kt, q)                                                   \
    GLDS16(aS + (size_t)((q) * 32) * KDIM + (kt) * 64,                         \
           ldsA + (cur) * 32768 + aDst + (q) * 4096);

#define RD_A(cur, m, ks) (*(const short8*)(ldsA + (cur) * 32768 + wr * 16384 + \
                          (m) * 2048 + (rdBase0 ^ ((ks) * 64))))
#define RD_B(cur, n, ks) (*(const short8*)(ldsB + (cur) * 32768 + wc * 8192 +  \
                          (n) * 2048 + (rdBase0 ^ ((ks) * 64))))

#define VMW(N) asm volatile("s_waitcnt vmcnt(" N ")" ::: "memory");

// Phases = (ks, mh): reads 8/4/8/4 per phase (LDS pipe balanced), issues
// (4,2,2,0), waits vmcnt(4)@p0 + vmcnt(2)@p3 only.
// Per-wave load queue per tile: [B1 B2 B3 B4 | A0 A1 | A2 A3].
// Drain map (steady state, entering tile with {A2,A3} outstanding):
//   p0: issue B*4 -> 6 out; vmcnt(4) drains A2,A3 (read by p1)
//   p1: issue A0,A1 -> 6 out
//   p2: issue A2,A3 -> 8 out
//   p3: vmcnt(2) drains B*4,A0,A1 of next tile (read by its p0/p1)
#define PHASE(cur, ks, mh, ISSUE, WAIT) {                                      \
  short8 af[4];                                                                \
  _Pragma("unroll")                                                            \
  for (int i = 0; i < 4; ++i) af[i] = RD_A(cur, (mh) * 4 + i, ks);             \
  if ((mh) == 0) {                                                             \
    _Pragma("unroll")                                                          \
    for (int n = 0; n < 4; ++n) bf[n] = RD_B(cur, n, ks);                      \
  }                                                                            \
  ISSUE                                                                        \
  __builtin_amdgcn_s_barrier();                                                \
  __builtin_amdgcn_s_setprio(1);                                               \
  _Pragma("unroll")                                                            \
  for (int i = 0; i < 4; ++i)                                                  \
    _Pragma("unroll")                                                          \
    for (int n = 0; n < 4; ++n)                                                \
      acc[(mh) * 4 + i][n] = __builtin_amdgcn_mfma_f32_16x16x32_bf16(          \
          af[i], bf[n], acc[(mh) * 4 + i][n], 0, 0, 0);                        \
  __builtin_amdgcn_s_setprio(0);                                               \
  WAIT                                                                         \
  __builtin_amdgcn_s_barrier(); }

#define TILE(cur, kt) { short8 bf[4];                                          \
  PHASE(cur, 0, 0, STAGE_B4((cur) ^ 1, (kt) + 1);, VMW("4"))                   \
  PHASE(cur, 0, 1, STAGE_A1((cur) ^ 1, (kt) + 1, 0); STAGE_A1((cur) ^ 1, (kt) + 1, 1);, ) \
  PHASE(cur, 1, 0, STAGE_A1((cur) ^ 1, (kt) + 1, 2); STAGE_A1((cur) ^ 1, (kt) + 1, 3);, ) \
  PHASE(cur, 1, 1, , VMW("2")) }

// Last tile: nothing issued; entering with {A2,A3} outstanding -> exact drain.
#define TILE_LAST(cur) { short8 bf[4];                                         \
  PHASE(cur, 0, 0, , VMW("0"))                                                 \
  PHASE(cur, 0, 1, , )                                                         \
  PHASE(cur, 1, 0, , )                                                         \
  PHASE(cur, 1, 1, , ) }

  // prologue: tile 0's strips in queue order [B x4, A0..A3]
  STAGE_B4(0, 0);
  STAGE_A1(0, 0, 0);
  STAGE_A1(0, 0, 1);
  STAGE_A1(0, 0, 2);
  STAGE_A1(0, 0, 3);
  VMW("2")   // drain B*4, A0, A1 (p0/p1 of tile 0); leave A2,A3 in flight
  __builtin_amdgcn_s_barrier();

  for (int kt = 0; kt < NT - 2; kt += 2) {
    TILE(0, kt)
    TILE(1, kt + 1)
  }
  TILE(0, NT - 2)
  TILE_LAST(1)

  // epilogue: bias + fp32 store (C/D map: col=lane&15, row=(lane>>4)*4+j)
#pragma unroll
  for (int m = 0; m < 8; ++m) {
    const int row0 = bm * 256 + wr * 128 + m * 16 + lh * 4;
#pragma unroll
    for (int n = 0; n < 4; ++n) {
      const int col = bn * 256 + wc * 64 + n * 16 + l15;
      const float bv_ = bias_v[n];
#pragma unroll
      for (int j = 0; j < 4; ++j)
        out[(size_t)(row0 + j) * NDIM + col] = acc[m][n][j] + bv_;
    }
  }
#undef TILE_LAST
#undef TILE
#undef PHASE
#undef VMW
#undef RD_A
#undef RD_B
#undef STAGE_A1
#undef STAGE_B4
}

// ---------------- fallback: fused single-pass (round-1 kernel) ----------------
__global__ __launch_bounds__(256, 2) void clinear_fused(
    const float* __restrict__ x,
    const int* __restrict__ qw,
    const float* __restrict__ scale,
    const float* __restrict__ bias,
    float* __restrict__ out)
{
  __shared__ unsigned char ldsA[128 * 64 * 2];
  __shared__ unsigned char ldsB[128 * 64 * 2];

  const int t = threadIdx.x;
  const int lane = t & 63;
  const int wave = t >> 6;
  const int wr = wave >> 1;
  const int wc = wave & 1;

  const int NBN = NDIM / 128;
  const int bid = blockIdx.x;
  const int cpx = ((MDIM / 128) * NBN) >> 3;
  const int swz = (bid & 7) * cpx + (bid >> 3);
  const int bm = swz / NBN;
  const int bn = swz % NBN;

  const int srow = t >> 1;
  const int shalf = t & 1;
  const float* aptr = x  + (size_t)(bm * 128 + srow) * KDIM + shalf * 32;
  const int*   bptr = qw + (size_t)(bn * 128 + srow) * KDIM + shalf * 32;
  const float* sptr = scale + (size_t)(bn * 128 + srow) * (KDIM / 256);
  const int arx = srow & 7;

  f32x4 acc[4][4];
#pragma unroll
  for (int i = 0; i < 4; ++i)
#pragma unroll
    for (int j = 0; j < 4; ++j)
      acc[i][j] = (f32x4){0.f, 0.f, 0.f, 0.f};

  float bias_v[4];
#pragma unroll
  for (int n = 0; n < 4; ++n)
    bias_v[n] = bias[bn * 128 + wc * 64 + n * 16 + (lane & 15)];

  for (int kt = 0; kt < KDIM / 64; ++kt) {
    const int k0 = kt * 64;
    float4v av[8];
    int4v   bv[8];
#pragma unroll
    for (int j = 0; j < 8; ++j) av[j] = *(const float4v*)(aptr + k0 + 4 * j);
#pragma unroll
    for (int j = 0; j < 8; ++j) bv[j] = *(const int4v*)(bptr + k0 + 4 * j);
    const float inv = 1.0f / sptr[k0 >> 8];

    __syncthreads();
#pragma unroll
    for (int c = 0; c < 4; ++c) {
      short8 pa, pb;
#pragma unroll
      for (int e = 0; e < 8; ++e) {
        const int v = c * 8 + e;
        pa[e] = (short)f2bf(av[v >> 2][v & 3]);
        pb[e] = (short)f2bf((float)bv[v >> 2][v & 3] * inv);
      }
      const int cc = shalf * 4 + c;
      *(short8*)(ldsA + srow * 128 + ((cc ^ arx) << 4)) = pa;
      *(short8*)(ldsB + srow * 128 + ((cc ^ arx) << 4)) = pb;
    }
    __syncthreads();

    short8 af[4][2], bfr[4][2];
#pragma unroll
    for (int m = 0; m < 4; ++m) {
      const int r = wr * 64 + m * 16 + (lane & 15);
      const int rx = r & 7;
#pragma unroll
      for (int ks = 0; ks < 2; ++ks) {
        const int ch = ks * 4 + (lane >> 4);
        af[m][ks] = *(const short8*)(ldsA + r * 128 + ((ch ^ rx) << 4));
      }
    }
#pragma unroll
    for (int n = 0; n < 4; ++n) {
      const int r = wc * 64 + n * 16 + (lane & 15);
      const int rx = r & 7;
#pragma unroll
      for (int ks = 0; ks < 2; ++ks) {
        const int ch = ks * 4 + (lane >> 4);
        bfr[n][ks] = *(const short8*)(ldsB + r * 128 + ((ch ^ rx) << 4));
      }
    }
#pragma unroll
    for (int ks = 0; ks < 2; ++ks)
#pragma unroll
      for (int m = 0; m < 4; ++m)
#pragma unroll
        for (int n = 0; n < 4; ++n)
          acc[m][n] = __builtin_amdgcn_mfma_f32_16x16x32_bf16(
              af[m][ks], bfr[n][ks], acc[m][n], 0, 0, 0);
  }

#pragma unroll
  for (int m = 0; m < 4; ++m) {
    const int row0 = bm * 128 + wr * 64 + m * 16 + (lane >> 4) * 4;
#pragma unroll
    for (int n = 0; n < 4; ++n) {
      const int col = bn * 128 + wc * 64 + n * 16 + (lane & 15);
      const float bv_ = bias_v[n];
#pragma unroll
      for (int j = 0; j < 4; ++j)
        out[(size_t)(row0 + j) * NDIM + col] = acc[m][n][j] + bv_;
    }
  }
}

extern "C" void kernel_launch(void* const* d_in, const int* in_sizes, int n_in,
                              void* d_out, int out_size, void* d_ws, size_t ws_size,
                              hipStream_t stream) {
  const float* x     = (const float*)d_in[0];
  const int*   qw    = (const int*)d_in[1];
  const float* scale = (const float*)d_in[2];
  const float* bias  = (const float*)d_in[3];
  float* out = (float*)d_out;

  const size_t needX = (size_t)MDIM * KDIM * sizeof(unsigned short);
  const size_t needW = (size_t)NDIM * KDIM * sizeof(unsigned short);

  if (ws_size >= needX + needW) {
    unsigned short* xb   = (unsigned short*)d_ws;
    unsigned short* wbuf = (unsigned short*)((char*)d_ws + needX);
    hipLaunchKernelGGL(conv_all, dim3(XBLOCKS + WBLOCKS), dim3(256), 0, stream,
                       x, xb, qw, scale, wbuf);
    hipLaunchKernelGGL(gemm256, dim3(NBM2 * NBN2), dim3(512), 0, stream,
                       xb, wbuf, bias, out);
  } else {
    hipLaunchKernelGGL(clinear_fused, dim3((MDIM / 128) * (NDIM / 128)), dim3(256),
                       0, stream, x, qw, scale, bias, out);
  }
}